// Round 3
// baseline (429.534 us; speedup 1.0000x reference)
//
#include <hip/hip_runtime.h>
#include <stdint.h>
#include <stddef.h>

// ---------------- problem constants ----------------
constexpr int kH = 496, kW = 432;
constexpr int HWSZ = kH * kW;          // 214272
constexpr int NANCH = HWSZ * 6;        // 1285632 anchors
constexpr int NPRE = 4096;             // nms_pre
constexpr int MAXNUM = 500;
constexpr int CAND_CAP = 8192;
constexpr float SCORE_THR_F = 0.1f;
constexpr float PIF  = 3.14159265358979323846f;
constexpr float HPIF = 1.57079632679489661923f;

constexpr int NBINS  = 32768;
constexpr int NPAIR  = NBINS / 2;      // packed u16 pairs in LDS = 64 KB
constexpr uint64_t PADKEY = 0xFFFFFFFF00000000ull;

// persistent-grid config: 128 blocks x 256 thr; 129KB LDS -> 1 block/CU,
// 128 <= 256 CUs => co-residency guaranteed with 2x margin.
constexpr int NBLK = 128;
constexpr int NTHR = 256;
constexpr uint64_t MAGIC = 0xA5C39E17D2B84F61ull;  // distinct bytes: can't be byte-fill poison
constexpr int NTASKC = (NANCH + 4095) / 4096;      // 314 compact tasks

// ---------------- workspace layout (bytes) ----------------
constexpr size_t HIST_OFF  = 0;                                   // u32[32768]
constexpr size_t MISC_OFF  = 131072;                              // u32[64]: 0=cand_cnt 8..10=Vc
constexpr size_t MS_OFF    = 131328;                              // f32[NANCH]
constexpr size_t CAND_OFF  = MS_OFF + 4ull * NANCH;               // u64[8192]
constexpr size_t SEL_OFF   = CAND_OFF + 8ull * CAND_CAP;          // (unused, layout keep)
constexpr size_t SC3_OFF   = SEL_OFF + 4ull * NPRE;               // f32[NPRE*3]
constexpr size_t DSC_OFF   = SC3_OFF + 4ull * NPRE * 3;           // u32[NPRE]
constexpr size_t BB7_OFF   = DSC_OFF + 4ull * NPRE;               // f32[NPRE*7]
constexpr size_t BOX4_OFF  = BB7_OFF + 4ull * NPRE * 7;           // f32[NPRE*4]
constexpr size_t AREA_OFF  = BOX4_OFF + 4ull * NPRE * 4;          // f32[NPRE]
constexpr size_t ORD_OFF   = AREA_OFF + 4ull * NPRE;              // u32[3*NPRE]
constexpr size_t VW_OFF    = ORD_OFF + 4ull * 3 * NPRE;           // u64[3*64]
constexpr size_t PMASK_OFF = VW_OFF + 8ull * 3 * 64;              // u64[3*NPRE*64] (6 MB)
constexpr size_t KEEPW_OFF = PMASK_OFF + 8ull * 3 * NPRE * 64;    // u64[3*64]
constexpr size_t OUTK_OFF  = KEEPW_OFF + 8ull * 3 * 64;           // u64[2048]
constexpr size_t DIAG_OFF  = OUTK_OFF + 8ull * 2048;              // u64[3*NPRE]
constexpr size_t BAR_OFF   = DIAG_OFF + 8ull * 3 * NPRE;          // u32[16]
constexpr size_t FLAG_OFF  = BAR_OFF + 64;                        // u64[1]

// ---------------- helpers ----------------
__device__ __forceinline__ float sigmoidf_(float x) { return 1.0f / (1.0f + expf(-x)); }

__device__ __forceinline__ uint64_t readlane64(uint64_t v, int lane) {
  uint32_t lo = (uint32_t)__builtin_amdgcn_readlane((int)(uint32_t)(v & 0xffffffffull), lane);
  uint32_t hi = (uint32_t)__builtin_amdgcn_readlane((int)(uint32_t)(v >> 32), lane);
  return (((uint64_t)hi) << 32) | (uint64_t)lo;
}

__device__ __forceinline__ void gl_lds16(const uint64_t* g, void* l) {
  __builtin_amdgcn_global_load_lds(
      (const __attribute__((address_space(1))) void*)g,
      (__attribute__((address_space(3))) void*)l, 16, 0, 0);
}
__device__ __forceinline__ void gl_lds4(const uint32_t* g, void* l) {
  __builtin_amdgcn_global_load_lds(
      (const __attribute__((address_space(1))) void*)g,
      (__attribute__((address_space(3))) void*)l, 4, 0, 0);
}

// device-scope grid barrier. Release: per-block threadfence (L2 wb) + relaxed
// arrive. Spin: RELAXED polls + s_sleep (no buffer_inv hammering while other
// blocks compute). Acquire: one threadfence after release observed.
__device__ __forceinline__ void gsync(uint32_t* bar, int idx) {
  __syncthreads();
  if (threadIdx.x == 0) {
    __threadfence();
    __hip_atomic_fetch_add(&bar[idx], 1u, __ATOMIC_RELAXED, __HIP_MEMORY_SCOPE_AGENT);
    while (__hip_atomic_load(&bar[idx], __ATOMIC_RELAXED, __HIP_MEMORY_SCOPE_AGENT) < (uint32_t)NBLK)
      __builtin_amdgcn_s_sleep(8);
    __threadfence();
  }
  __syncthreads();
}

// ---------------- the single fused kernel ----------------
__global__ __launch_bounds__(NTHR) void k_all(const float* __restrict__ cls,
                                              const float* __restrict__ bbp,
                                              const float* __restrict__ dirp,
                                              const float* __restrict__ priors,
                                              char* __restrict__ ws,
                                              float* __restrict__ out) {
  __shared__ __align__(16) uint8_t SMEM[132096];  // 129 KB union

  uint32_t* hist  = (uint32_t*)(ws + HIST_OFF);
  uint32_t* misc  = (uint32_t*)(ws + MISC_OFF);
  float*    ms    = (float*)(ws + MS_OFF);
  uint64_t* cand  = (uint64_t*)(ws + CAND_OFF);
  float*    sc3   = (float*)(ws + SC3_OFF);
  uint32_t* dsc   = (uint32_t*)(ws + DSC_OFF);
  float*    bb7   = (float*)(ws + BB7_OFF);
  float*    box4  = (float*)(ws + BOX4_OFF);
  float*    areaA = (float*)(ws + AREA_OFF);
  uint32_t* ord   = (uint32_t*)(ws + ORD_OFF);
  unsigned long long* vw = (unsigned long long*)(ws + VW_OFF);
  uint64_t* pmask = (uint64_t*)(ws + PMASK_OFF);
  uint64_t* keepw = (uint64_t*)(ws + KEEPW_OFF);
  uint64_t* outk  = (uint64_t*)(ws + OUTK_OFF);
  uint64_t* diagv = (uint64_t*)(ws + DIAG_OFF);
  uint32_t* bar   = (uint32_t*)(ws + BAR_OFF);
  unsigned long long* flag = (unsigned long long*)(ws + FLAG_OFF);

  const int b = blockIdx.x, t = threadIdx.x;
  const int wv = t >> 6, ln = t & 63;
  const int wgid = b * 4 + wv;   // 0..511
  const int gid = b * NTHR + t;  // 0..32767

  // ---- barrier init behind magic flag (ws is poisoned every launch) ----
  if (b == 0 && t == 0) {
    for (int i = 0; i < 16; ++i) bar[i] = 0;
    __threadfence();
    __hip_atomic_store(flag, MAGIC, __ATOMIC_RELAXED, __HIP_MEMORY_SCOPE_AGENT);
  }
  if (t == 0) {
    while (__hip_atomic_load(flag, __ATOMIC_RELAXED, __HIP_MEMORY_SCOPE_AGENT) != MAGIC)
      __builtin_amdgcn_s_sleep(2);
    __threadfence();
  }

  // =========== P0: zero (hist/misc/vw) + score + LDS histogram ===========
  {
    uint32_t* h = (uint32_t*)SMEM;  // 64 KB packed u16 pairs
    for (int i = t; i < NPAIR; i += NTHR) h[i] = 0;
    if (gid < NBINS) hist[gid] = 0;
    if (gid < 64) misc[gid] = 0;
    if (gid < 384) ((uint32_t*)vw)[gid] = 0;
    __syncthreads();
    for (int p = b * NTHR + t; p < HWSZ; p += NBLK * NTHR) {
#pragma unroll
      for (int k = 0; k < 6; ++k) {
        float s0 = sigmoidf_(cls[(k * 3 + 0) * HWSZ + p]);
        float s1 = sigmoidf_(cls[(k * 3 + 1) * HWSZ + p]);
        float s2 = sigmoidf_(cls[(k * 3 + 2) * HWSZ + p]);
        float m = fmaxf(s0, fmaxf(s1, s2));
        ms[p * 6 + k] = m;
        uint32_t bin = __float_as_uint(m) >> 15;
        atomicAdd(&h[bin >> 1], 1u << ((bin & 1) * 16));
      }
    }
    gsync(bar, 0);  // all zeroing done + local hists built
    for (int i = t; i < NPAIR; i += NTHR) {
      uint32_t v = h[i];
      if (v) {
        uint32_t lo = v & 0xFFFFu, hi = v >> 16;
        if (lo) atomicAdd(&hist[2 * i],     lo);
        if (hi) atomicAdd(&hist[2 * i + 1], hi);
      }
    }
  }
  gsync(bar, 1);  // hist final, ms final

  // =========== P1: threshold scan (per block) + compact ===========
  {
    uint64_t* lbuf = (uint64_t*)SMEM;                 // 32 KB
    uint32_t* suf  = (uint32_t*)(SMEM + 32768);
    uint32_t* win  = (uint32_t*)(SMEM + 33792);
    uint32_t* scal = (uint32_t*)(SMEM + 34816);       // 0=lcnt 1=lbase 2=sWin 3=sAbove 4=sB

    uint32_t s = 0;
    const int hbase = t * 128;
#pragma unroll 16
    for (int i = 0; i < 128; ++i) s += hist[hbase + i];
    suf[t] = s;
    if (t == 0) scal[4] = 0;
    __syncthreads();
    for (int d = 1; d < 256; d <<= 1) {
      uint32_t v = suf[t] + ((t + d < 256) ? suf[t + d] : 0u);
      __syncthreads(); suf[t] = v; __syncthreads();
    }
    {
      uint32_t sin = suf[t];
      uint32_t sup = (t < 255) ? suf[t + 1] : 0u;
      if (sin >= (uint32_t)NPRE && sup < (uint32_t)NPRE) { scal[2] = (uint32_t)t; scal[3] = sup; }
    }
    __syncthreads();
    const uint32_t wbase = scal[2] * 128u, sAbove = scal[3];
    win[t] = (t < 128) ? hist[wbase + (uint32_t)t] : 0u;
    __syncthreads();
    for (int d = 1; d < 256; d <<= 1) {
      uint32_t v = win[t] + ((t + d < 256) ? win[t + d] : 0u);
      __syncthreads(); win[t] = v; __syncthreads();
    }
    if (t < 128 && sAbove + win[t] >= (uint32_t)NPRE)
      atomicMax(&scal[4], wbase + (uint32_t)t);
    __syncthreads();
    const uint32_t B = scal[4];

    for (int task = b; task < NTASKC; task += NBLK) {
      const int base = task * 4096;
      if (t == 0) scal[0] = 0;
      __syncthreads();
#pragma unroll
      for (int q = 0; q < 16; ++q) {
        int a = base + q * NTHR + t;
        if (a < NANCH) {
          uint32_t bits = __float_as_uint(ms[a]);
          if ((bits >> 15) >= B) {
            uint32_t sl = atomicAdd(&scal[0], 1u);
            lbuf[sl] = (((uint64_t)(~bits)) << 32) | (uint32_t)a;
          }
        }
      }
      __syncthreads();
      const uint32_t n = scal[0];
      if (t == 0 && n > 0) scal[1] = atomicAdd(&misc[0], n);
      __syncthreads();
      if (n > 0) {
        const uint32_t b0 = scal[1];
        for (uint32_t i = t; i < n; i += NTHR) {
          uint32_t slot = b0 + i;
          if (slot < (uint32_t)CAND_CAP) cand[slot] = lbuf[i];
        }
      }
      __syncthreads();
    }
  }
  gsync(bar, 2);  // cand + misc[0] final

  // =========== P2: global rank (top-4096) + FUSED gather/decode ===========
  {
    uint32_t cnt = misc[0];
    if (cnt > (uint32_t)CAND_CAP) cnt = CAND_CAP;
    const int base = wgid * 16;  // 512 waves x 16 rows = 8192
    uint64_t kr[16];
#pragma unroll
    for (int r = 0; r < 16; ++r) kr[r] = cand[base + r];
    uint32_t rnk[16];
#pragma unroll
    for (int r = 0; r < 16; ++r) rnk[r] = 0;
    const int nch = ((int)cnt + 63) >> 6;
#pragma unroll 4
    for (int ch = 0; ch < nch; ++ch) {
      uint64_t ck = cand[ch * 64 + ln];
      uint64_t vm = __ballot(ch * 64 + ln < (int)cnt);
#pragma unroll
      for (int r = 0; r < 16; ++r)
        rnk[r] += (uint32_t)__popcll(__ballot(ck < kr[r]) & vm);
    }
    // rnk/kr are wave-uniform: lane r decodes row r (static select, no scratch)
    uint32_t my_a = 0, my_rnk = 0; int my_ok = 0;
#pragma unroll
    for (int r = 0; r < 16; ++r) {
      int ok = (base + r < (int)cnt) && (rnk[r] < (uint32_t)NPRE);
      if (ln == r) { my_a = (uint32_t)kr[r]; my_rnk = rnk[r]; my_ok = ok; }
    }
    if (ln < 16 && my_ok) {
      uint32_t a = my_a, i = my_rnk;
      uint32_t p = a / 6u;
      uint32_t k = a - p * 6u;
#pragma unroll
      for (int c = 0; c < 3; ++c) sc3[i * 3 + c] = sigmoidf_(cls[(k * 3 + c) * HWSZ + p]);
      float d0 = dirp[(k * 2 + 0) * HWSZ + p];
      float d1 = dirp[(k * 2 + 1) * HWSZ + p];
      dsc[i] = (d1 > d0) ? 1u : 0u;
      float dt[7], pr[7];
#pragma unroll
      for (int q = 0; q < 7; ++q) dt[q] = bbp[(k * 7 + q) * HWSZ + p];
#pragma unroll
      for (int q = 0; q < 7; ++q) pr[q] = priors[(size_t)a * 7 + q];
      float za = pr[2] + pr[5] * 0.5f;
      float diag = sqrtf(pr[4] * pr[4] + pr[3] * pr[3]);
      float xg = dt[0] * diag + pr[0];
      float yg = dt[1] * diag + pr[1];
      float zg = dt[2] * pr[5] + za;
      float wg = expf(dt[3]) * pr[3];
      float lg = expf(dt[4]) * pr[4];
      float hg = expf(dt[5]) * pr[5];
      float rg = dt[6] + pr[6];
      zg = zg - hg * 0.5f;
      bb7[i * 7 + 0] = xg; bb7[i * 7 + 1] = yg; bb7[i * 7 + 2] = zg;
      bb7[i * 7 + 3] = wg; bb7[i * 7 + 4] = lg; bb7[i * 7 + 5] = hg; bb7[i * 7 + 6] = rg;
      float x1 = xg - wg * 0.5f, y1 = yg - lg * 0.5f;
      float x2 = xg + wg * 0.5f, y2 = yg + lg * 0.5f;
      box4[i * 4 + 0] = x1; box4[i * 4 + 1] = y1; box4[i * 4 + 2] = x2; box4[i * 4 + 3] = y2;
      areaA[i] = (x2 - x1 + 1.0f) * (y2 - y1 + 1.0f);
    }
  }
  gsync(bar, 3);  // sc3/dsc/bb7/box4/area final

  // =========== P3: per-class rank -> ord + vwords scatter ===========
  for (int task = wgid; task < 768; task += 512) {
    const int c = task >> 8;
    const int base = (task & 255) * 16;
    uint64_t kr[16];
#pragma unroll
    for (int r = 0; r < 16; ++r) {
      int j = base + r;
      kr[r] = (((uint64_t)(~__float_as_uint(sc3[j * 3 + c]))) << 32) | (uint32_t)j;
    }
    uint32_t rnk[16];
#pragma unroll
    for (int r = 0; r < 16; ++r) rnk[r] = 0;
#pragma unroll 4
    for (int ch = 0; ch < NPRE / 64; ++ch) {
      int j = ch * 64 + ln;
      uint64_t ck = (((uint64_t)(~__float_as_uint(sc3[j * 3 + c]))) << 32) | (uint32_t)j;
#pragma unroll
      for (int r = 0; r < 16; ++r)
        rnk[r] += (uint32_t)__popcll(__ballot(ck < kr[r]));
    }
    uint32_t my_rnk = 0; int my_v = 0;
#pragma unroll
    for (int r = 0; r < 16; ++r) {
      uint32_t sb = ~(uint32_t)(kr[r] >> 32);
      int v = __uint_as_float(sb) > SCORE_THR_F;
      if (ln == r) { my_rnk = rnk[r]; my_v = v; }
    }
    if (ln < 16) {
      ord[c * NPRE + my_rnk] = (uint32_t)(base + ln);
      if (my_v) atomicOr(&vw[c * 64 + (my_rnk >> 6)], 1ull << (my_rnk & 63));
    }
  }
  gsync(bar, 4);  // ord + vwords final

  // =========== P4: suppression bitmask (upper triangle) + diag ===========
  {
    float* sl = (float*)(SMEM + wv * 1280);  // per-wave slice: 5 x 64 f32
    float* jx1 = sl, *jy1 = sl + 64, *jx2 = sl + 128, *jy2 = sl + 192, *jar = sl + 256;
    for (int task = wgid; task < 6240; task += 512) {
      int c = task / 2080;
      int rr = task - c * 2080;
      int it = 0;
      while (rr >= 64 - it) { rr -= 64 - it; ++it; }
      int jt = it + rr;

      int j = ord[c * NPRE + jt * 64 + ln];
      jx1[ln] = box4[j * 4 + 0]; jy1[ln] = box4[j * 4 + 1];
      jx2[ln] = box4[j * 4 + 2]; jy2[ln] = box4[j * 4 + 3];
      jar[ln] = areaA[j];
      int I = it * 64 + ln;
      int i = ord[c * NPRE + I];
      float x1 = box4[i * 4 + 0], y1 = box4[i * 4 + 1];
      float x2 = box4[i * 4 + 2], y2 = box4[i * 4 + 3];
      float ar = areaA[i];
      uint64_t bits = 0;
      for (int bb = 0; bb < 64; ++bb) {
        float xx1 = fmaxf(x1, jx1[bb]), yy1 = fmaxf(y1, jy1[bb]);
        float xx2 = fminf(x2, jx2[bb]), yy2 = fminf(y2, jy2[bb]);
        float iw = fmaxf(0.0f, xx2 - xx1 + 1.0f);
        float ih = fmaxf(0.0f, yy2 - yy1 + 1.0f);
        float inter = iw * ih;
        float iou = inter / (ar + jar[bb] - inter);
        bits |= ((uint64_t)(iou > 0.5f)) << bb;
      }
      pmask[((size_t)(c * NPRE + I)) * 64 + (size_t)jt] = bits;
      if (jt == it) diagv[(size_t)c * NPRE + (size_t)I] = bits;
    }
  }
  gsync(bar, 5);  // pmask + diag final

  // =========== P5: single-wave sparse greedy NMS (counted-vmcnt ring) ======
  if (b < 3 && t < 64) {
    const int c = b;
    const uint64_t* pm = pmask + (size_t)c * NPRE * 64;
    uint64_t* lb = (uint64_t*)SMEM;                    // 3 x 32 KB ring
    uint64_t* dl = (uint64_t*)(SMEM + 98304);          // 32 KB diag
    uint64_t* avl = (uint64_t*)(SMEM + 131072);        // 512 B valid words

    // issue: avail(2 x 4B) + diag(32) + tile0(32) + tile1(32)
    const uint32_t* vw32 = (const uint32_t*)(vw + (size_t)c * 64);
    gl_lds4(vw32 + ln, avl);
    gl_lds4(vw32 + 64 + ln, (uint8_t*)avl + 256);
    const uint64_t* gd = diagv + (size_t)c * NPRE;
#pragma unroll
    for (int i = 0; i < 32; ++i) gl_lds16(gd + i * 128 + ln * 2, dl + i * 128);
#pragma unroll
    for (int i = 0; i < 32; ++i) gl_lds16(pm + i * 128 + ln * 2, lb + i * 128);
#pragma unroll
    for (int i = 0; i < 32; ++i) gl_lds16(pm + 4096 + i * 128 + ln * 2, lb + 4096 + i * 128);
    asm volatile("s_waitcnt vmcnt(32)" ::: "memory");  // avail+diag+tile0 done
    __builtin_amdgcn_sched_barrier(0);

    uint64_t avail = avl[ln];
    uint64_t dgc = dl[ln];
    uint64_t mykeep = 0;
    int cnt = 0;
    for (int T = 0; T < 64; ++T) {
      if (T > 0) {
        if (T < 63) { asm volatile("s_waitcnt vmcnt(32)" ::: "memory"); }
        else        { asm volatile("s_waitcnt vmcnt(0)"  ::: "memory"); }
        __builtin_amdgcn_sched_barrier(0);
      }
      const uint64_t* tb = lb + (size_t)(T % 3) * 4096;

      uint64_t awT = readlane64(avail, T);
      uint64_t kwT = 0;
      while (awT) {                        // each visited row IS a keep
        int r = (int)__builtin_ctzll(awT);
        kwT |= (1ull << r);
        awT &= ~(1ull << r);
        awT &= ~readlane64(dgc, r);
      }
      uint64_t dgn = 0;
      if (T + 1 < 64) dgn = dl[(T + 1) * 64 + ln];

      if (kwT) {
        uint64_t supp = 0, k = kwT;
        while (k) {
          int r0 = (int)__builtin_ctzll(k); k &= k - 1;
          int r1 = k ? (int)__builtin_ctzll(k) : r0; if (k) k &= k - 1;
          int r2 = k ? (int)__builtin_ctzll(k) : r1; if (k) k &= k - 1;
          int r3 = k ? (int)__builtin_ctzll(k) : r2; if (k) k &= k - 1;
          supp |= tb[r0 * 64 + ln] | tb[r1 * 64 + ln] |
                  tb[r2 * 64 + ln] | tb[r3 * 64 + ln];
        }
        avail &= ~supp;  // lower-triangle garbage only hits lanes<T (fixed)
        if (ln == T) mykeep = kwT;
        cnt += (int)__popcll(kwT);
        if (cnt >= MAXNUM) break;
      }
      dgc = dgn;

      if (T + 2 < 64) {
        uint64_t* dst = lb + (size_t)((T + 2) % 3) * 4096;
        const uint64_t* gb = pm + ((size_t)(T + 2) << 12);
#pragma unroll
        for (int i = 0; i < 32; ++i) gl_lds16(gb + i * 128 + ln * 2, dst + i * 128);
      }
    }
    asm volatile("s_waitcnt vmcnt(0)" ::: "memory");
    keepw[c * 64 + ln] = mykeep;
  }
  gsync(bar, 6);  // keepw final

  // =========== P6: per-class stable compact -> outk ===========
  if (b < 3) {
    const int c = b;
    uint32_t* wsum = (uint32_t*)SMEM;  // 4 u32
    uint32_t bits16 = (uint32_t)((keepw[c * 64 + (t >> 2)] >> ((t & 3) * 16)) & 0xFFFFull);
    uint32_t cnt = __popc(bits16);
    uint32_t incl = cnt;
#pragma unroll
    for (int d = 1; d < 64; d <<= 1) { uint32_t u = __shfl_up(incl, d, 64); if (ln >= d) incl += u; }
    if (ln == 63) wsum[wv] = incl;
    __syncthreads();
    uint32_t wb = 0, total = 0;
#pragma unroll
    for (int i = 0; i < 4; ++i) { uint32_t v = wsum[i]; total += v; if (i < wv) wb += v; }
    uint32_t r = wb + incl - cnt;  // exclusive prefix
#pragma unroll
    for (int q = 0; q < 16; ++q) {
      if ((bits16 >> q) & 1u) {
        if (r < (uint32_t)MAXNUM) {
          uint32_t pos = ord[c * NPRE + t * 16 + q];
          uint32_t sb = __float_as_uint(sc3[pos * 3 + c]);
          outk[c * MAXNUM + r] = (((uint64_t)(~sb)) << 32) | (uint32_t)(c * NPRE + pos);
        }
        ++r;
      }
    }
    uint32_t Vc = total < (uint32_t)MAXNUM ? total : (uint32_t)MAXNUM;
    if (t == 0) misc[8 + c] = Vc;
    for (uint32_t s = Vc + t; s < (uint32_t)MAXNUM; s += NTHR)
      outk[c * MAXNUM + s] = PADKEY;
  } else if (b == 3) {
    for (int i = 3 * MAXNUM + t; i < 2048; i += NTHR) outk[i] = PADKEY;
  }
  gsync(bar, 7);  // outk + misc[8..10] final

  // =========== P7: rank 2048-key union -> emit ===========
  if (wgid < 128) {
    const int base = wgid * 16;
    uint64_t kr[16];
#pragma unroll
    for (int r = 0; r < 16; ++r) kr[r] = outk[base + r];
    uint32_t rnk[16];
#pragma unroll
    for (int r = 0; r < 16; ++r) rnk[r] = 0;
#pragma unroll 4
    for (int ch = 0; ch < 2048 / 64; ++ch) {
      uint64_t ck = outk[ch * 64 + ln];
#pragma unroll
      for (int r = 0; r < 16; ++r)
        rnk[r] += (uint32_t)__popcll(__ballot(ck < kr[r]));
    }
    if (ln == 0) {
#pragma unroll
      for (int r = 0; r < 16; ++r) {
        uint64_t key = kr[r];
        uint32_t rk = rnk[r];
        if (key != PADKEY && rk < (uint32_t)MAXNUM) {
          uint32_t flat = (uint32_t)key;
          float score = __uint_as_float(~((uint32_t)(key >> 32)));
          int cc = (int)(flat >> 12);
          int pos = (int)(flat & 4095u);
          const float* bx = bb7 + (size_t)pos * 7;
          float rr0 = bx[6];
          float dir_rot = rr0 + HPIF - floorf(rr0 + 0.5f) * PIF;
          float rrot = dir_rot - HPIF + PIF * (float)dsc[pos];
#pragma unroll
          for (int q = 0; q < 6; ++q) out[rk * 7 + q] = bx[q];
          out[rk * 7 + 6] = rrot;
          out[7 * MAXNUM + rk] = score;
          out[8 * MAXNUM + rk] = (float)cc;
        }
      }
    }
  }
  if (b == 0) {
    uint32_t V = misc[8] + misc[9] + misc[10];
    for (uint32_t s = V + t; s < (uint32_t)MAXNUM; s += NTHR) {
#pragma unroll
      for (int q = 0; q < 7; ++q) out[s * 7 + q] = 0.0f;
      out[7 * MAXNUM + s] = 0.0f;
      out[8 * MAXNUM + s] = -1.0f;
    }
  }
}

// ---------------- launcher: ONE dispatch, zero memsets ----------------
extern "C" void kernel_launch(void* const* d_in, const int* in_sizes, int n_in,
                              void* d_out, int out_size, void* d_ws, size_t ws_size,
                              hipStream_t stream) {
  (void)in_sizes; (void)n_in; (void)out_size; (void)ws_size;
  const float* cls    = (const float*)d_in[0];
  const float* bbp    = (const float*)d_in[1];
  const float* dirp   = (const float*)d_in[2];
  const float* priors = (const float*)d_in[3];
  k_all<<<NBLK, NTHR, 0, stream>>>(cls, bbp, dirp, priors, (char*)d_ws, (float*)d_out);
}

// Round 4
// 302.242 us; speedup vs baseline: 1.4212x; 1.4212x over previous
//
#include <hip/hip_runtime.h>
#include <stdint.h>
#include <stddef.h>

// ---------------- problem constants ----------------
constexpr int kH = 496, kW = 432;
constexpr int HWSZ = kH * kW;          // 214272
constexpr int NANCH = HWSZ * 6;        // 1285632 anchors
constexpr int NPRE = 4096;             // nms_pre
constexpr int MAXNUM = 500;
constexpr int CAND_CAP = 8192;
constexpr float SCORE_THR_F = 0.1f;
constexpr float PIF  = 3.14159265358979323846f;
constexpr float HPIF = 1.57079632679489661923f;

constexpr int NBINS  = 32768;
constexpr int NPAIR  = NBINS / 2;      // packed u16 pairs in LDS = 64 KB
constexpr int NB_H   = 256;            // histogram blocks
constexpr uint64_t PADKEY = 0xFFFFFFFF00000000ull;

// ---------------- workspace layout (bytes) ----------------
constexpr size_t HIST_OFF  = 0;                                   // u32[32768] = 128 KB
constexpr size_t MISC_OFF  = 131072;                              // u32[64]
constexpr size_t VW_OFF    = 131328;                              // u64[3*64] = 1536 B
constexpr size_t ZERO_BYTES= 131328 + 1536;                       // hist+misc+vw, ONE memset
constexpr size_t MS_OFF    = ZERO_BYTES;                          // f32[NANCH]
constexpr size_t CAND_OFF  = MS_OFF + 4ull * NANCH;               // u64[8192]
constexpr size_t SC3_OFF   = CAND_OFF + 8ull * CAND_CAP;          // f32[NPRE*3]
constexpr size_t DSC_OFF   = SC3_OFF + 4ull * NPRE * 3;           // u32[NPRE]
constexpr size_t BB7_OFF   = DSC_OFF + 4ull * NPRE;               // f32[NPRE*7]
constexpr size_t BOX4_OFF  = BB7_OFF + 4ull * NPRE * 7;           // f32[NPRE*4]
constexpr size_t AREA_OFF  = BOX4_OFF + 4ull * NPRE * 4;          // f32[NPRE]
constexpr size_t ORD_OFF   = AREA_OFF + 4ull * NPRE;              // u32[3*NPRE]
constexpr size_t PMASK_OFF = ORD_OFF + 4ull * 3 * NPRE;           // u64[3*NPRE*64] (6 MB)
constexpr size_t KEEPW_OFF = PMASK_OFF + 8ull * 3 * NPRE * 64;    // u64[3*64]
constexpr size_t OUTK_OFF  = KEEPW_OFF + 8ull * 3 * 64;           // u64[2048]
constexpr size_t DIAG_OFF  = OUTK_OFF + 8ull * 2048;              // u64[3*NPRE]

// ---------------- helpers ----------------
__device__ __forceinline__ float sigmoidf_(float x) { return 1.0f / (1.0f + expf(-x)); }

__device__ __forceinline__ uint64_t readlane64(uint64_t v, int lane) {
  uint32_t lo = (uint32_t)__builtin_amdgcn_readlane((int)(uint32_t)(v & 0xffffffffull), lane);
  uint32_t hi = (uint32_t)__builtin_amdgcn_readlane((int)(uint32_t)(v >> 32), lane);
  return (((uint64_t)hi) << 32) | (uint64_t)lo;
}

__device__ __forceinline__ void gl_lds16(const uint64_t* g, void* l) {
  __builtin_amdgcn_global_load_lds(
      (const __attribute__((address_space(1))) void*)g,
      (__attribute__((address_space(3))) void*)l, 16, 0, 0);
}
__device__ __forceinline__ void gl_lds4(const uint32_t* g, void* l) {
  __builtin_amdgcn_global_load_lds(
      (const __attribute__((address_space(1))) void*)g,
      (__attribute__((address_space(3))) void*)l, 4, 0, 0);
}

// ---------------- kernels ----------------

// 1) per-anchor max-of-3-sigmoids + per-block LDS histogram.
__global__ __launch_bounds__(256) void k_score(const float* __restrict__ cls,
                                               float* __restrict__ ms,
                                               uint32_t* __restrict__ hist) {
  __shared__ uint32_t h[NPAIR];  // 64 KB, packed u16 pairs
  const int t = threadIdx.x, blk = blockIdx.x;
  for (int i = t; i < NPAIR; i += 256) h[i] = 0;
  __syncthreads();
  for (int p = blk * 256 + t; p < HWSZ; p += NB_H * 256) {
#pragma unroll
    for (int k = 0; k < 6; ++k) {
      float s0 = sigmoidf_(cls[(k * 3 + 0) * HWSZ + p]);
      float s1 = sigmoidf_(cls[(k * 3 + 1) * HWSZ + p]);
      float s2 = sigmoidf_(cls[(k * 3 + 2) * HWSZ + p]);
      float m = fmaxf(s0, fmaxf(s1, s2));
      ms[p * 6 + k] = m;
      uint32_t bin = __float_as_uint(m) >> 15;  // < 32768 (scores < 2.0)
      atomicAdd(&h[bin >> 1], 1u << ((bin & 1) * 16));
    }
  }
  __syncthreads();
  for (int i = t; i < NPAIR; i += 256) {
    uint32_t v = h[i];
    if (v) {
      uint32_t lo = v & 0xFFFFu, hi = v >> 16;
      if (lo) atomicAdd(&hist[2 * i],     lo);
      if (hi) atomicAdd(&hist[2 * i + 1], hi);
    }
  }
}

// 2) block-aggregated compaction with FUSED threshold scan (hist L2-resident).
__global__ __launch_bounds__(256) void k_compact(const float* __restrict__ ms,
                                                 const uint32_t* __restrict__ hist,
                                                 uint32_t* __restrict__ misc,
                                                 uint64_t* __restrict__ cand) {
  constexpr int APB = 4096;
  __shared__ uint64_t lbuf[APB];       // 32 KB
  __shared__ uint32_t suf[256];
  __shared__ uint32_t win[256];
  __shared__ uint32_t lcnt, lbase, sWin, sAbove, sB;
  const int t = threadIdx.x;
  const int base = blockIdx.x * APB;

  uint32_t s = 0;
  const int hbase = t * 128;
#pragma unroll 16
  for (int i = 0; i < 128; ++i) s += hist[hbase + i];
  suf[t] = s;
  if (t == 0) { lcnt = 0; sB = 0; }
  __syncthreads();
  for (int d = 1; d < 256; d <<= 1) {
    uint32_t v = suf[t] + ((t + d < 256) ? suf[t + d] : 0u);
    __syncthreads(); suf[t] = v; __syncthreads();
  }
  {
    uint32_t sin = suf[t];
    uint32_t sup = (t < 255) ? suf[t + 1] : 0u;
    if (sin >= (uint32_t)NPRE && sup < (uint32_t)NPRE) { sWin = (uint32_t)t; sAbove = sup; }
  }
  __syncthreads();
  const uint32_t wbase = sWin * 128u;
  win[t] = (t < 128) ? hist[wbase + (uint32_t)t] : 0u;
  __syncthreads();
  for (int d = 1; d < 256; d <<= 1) {
    uint32_t v = win[t] + ((t + d < 256) ? win[t + d] : 0u);
    __syncthreads(); win[t] = v; __syncthreads();
  }
  if (t < 128 && sAbove + win[t] >= (uint32_t)NPRE)
    atomicMax(&sB, wbase + (uint32_t)t);
  __syncthreads();
  const uint32_t B = sB;

#pragma unroll
  for (int q = 0; q < 16; ++q) {
    int a = base + q * 256 + t;
    if (a < NANCH) {
      uint32_t bits = __float_as_uint(ms[a]);
      if ((bits >> 15) >= B) {
        uint32_t sl = atomicAdd(&lcnt, 1u);
        lbuf[sl] = (((uint64_t)(~bits)) << 32) | (uint32_t)a;
      }
    }
  }
  __syncthreads();
  const uint32_t n = lcnt;
  if (t == 0 && n > 0) lbase = atomicAdd(&misc[0], n);
  __syncthreads();
  if (n > 0) {
    const uint32_t b0 = lbase;
    for (uint32_t i = t; i < n; i += 256) {
      uint32_t slot = b0 + i;
      if (slot < (uint32_t)CAND_CAP) cand[slot] = lbuf[i];
    }
  }
}

// 3) FUSED rank + gather/decode: ranks are wave-uniform -> lane r decodes row r.
__global__ __launch_bounds__(256) void k_rankgather(const uint64_t* __restrict__ cand,
                                                    const uint32_t* __restrict__ misc,
                                                    const float* __restrict__ cls,
                                                    const float* __restrict__ bbp,
                                                    const float* __restrict__ dirp,
                                                    const float* __restrict__ priors,
                                                    float* __restrict__ sc3,
                                                    uint32_t* __restrict__ dsc,
                                                    float* __restrict__ bb7,
                                                    float* __restrict__ box4,
                                                    float* __restrict__ areaA) {
  const int tid = threadIdx.x, ln = tid & 63;
  const int wave = blockIdx.x * 4 + (tid >> 6);   // 0..511
  const int base = wave * 16;
  uint32_t cnt = misc[0];
  if (cnt > (uint32_t)CAND_CAP) cnt = CAND_CAP;
  uint64_t kr[16];
#pragma unroll
  for (int r = 0; r < 16; ++r) kr[r] = cand[base + r];
  uint32_t rnk[16];
#pragma unroll
  for (int r = 0; r < 16; ++r) rnk[r] = 0;
  const int nch = ((int)cnt + 63) >> 6;
  for (int ch = 0; ch < nch; ++ch) {
    uint64_t ck = cand[ch * 64 + ln];
    uint64_t vm = __ballot(ch * 64 + ln < (int)cnt);
#pragma unroll
    for (int r = 0; r < 16; ++r)
      rnk[r] += (uint32_t)__popcll(__ballot(ck < kr[r]) & vm);
  }
  uint32_t my_a = 0, my_i = 0; int my_ok = 0;
#pragma unroll
  for (int r = 0; r < 16; ++r) {
    int ok = (base + r < (int)cnt) && (rnk[r] < (uint32_t)NPRE);
    if (ln == r) { my_a = (uint32_t)kr[r]; my_i = rnk[r]; my_ok = ok; }
  }
  if (ln < 16 && my_ok) {
    uint32_t a = my_a, i = my_i;
    uint32_t p = a / 6u;
    uint32_t k = a - p * 6u;
#pragma unroll
    for (int c = 0; c < 3; ++c) sc3[i * 3 + c] = sigmoidf_(cls[(k * 3 + c) * HWSZ + p]);
    float d0 = dirp[(k * 2 + 0) * HWSZ + p];
    float d1 = dirp[(k * 2 + 1) * HWSZ + p];
    dsc[i] = (d1 > d0) ? 1u : 0u;
    float dt[7], pr[7];
#pragma unroll
    for (int q = 0; q < 7; ++q) dt[q] = bbp[(k * 7 + q) * HWSZ + p];
#pragma unroll
    for (int q = 0; q < 7; ++q) pr[q] = priors[(size_t)a * 7 + q];
    float za = pr[2] + pr[5] * 0.5f;
    float diag = sqrtf(pr[4] * pr[4] + pr[3] * pr[3]);
    float xg = dt[0] * diag + pr[0];
    float yg = dt[1] * diag + pr[1];
    float zg = dt[2] * pr[5] + za;
    float wg = expf(dt[3]) * pr[3];
    float lg = expf(dt[4]) * pr[4];
    float hg = expf(dt[5]) * pr[5];
    float rg = dt[6] + pr[6];
    zg = zg - hg * 0.5f;
    bb7[i * 7 + 0] = xg; bb7[i * 7 + 1] = yg; bb7[i * 7 + 2] = zg;
    bb7[i * 7 + 3] = wg; bb7[i * 7 + 4] = lg; bb7[i * 7 + 5] = hg; bb7[i * 7 + 6] = rg;
    float x1 = xg - wg * 0.5f, y1 = yg - lg * 0.5f;
    float x2 = xg + wg * 0.5f, y2 = yg + lg * 0.5f;
    box4[i * 4 + 0] = x1; box4[i * 4 + 1] = y1; box4[i * 4 + 2] = x2; box4[i * 4 + 3] = y2;
    areaA[i] = (x2 - x1 + 1.0f) * (y2 - y1 + 1.0f);
  }
}

// 4) per-class rank -> ord, + vwords bitset via atomicOr scatter (vw pre-zeroed).
__global__ __launch_bounds__(256) void k_rankcls(const float* __restrict__ sc3,
                                                 uint32_t* __restrict__ ord,
                                                 unsigned long long* __restrict__ vw) {
  const int tid = threadIdx.x, ln = tid & 63;
  const int c = blockIdx.y;
  const int wave = blockIdx.x * 4 + (tid >> 6);  // 0..255
  const int base = wave * 16;
  uint64_t kr[16];
#pragma unroll
  for (int r = 0; r < 16; ++r) {
    int j = base + r;
    kr[r] = (((uint64_t)(~__float_as_uint(sc3[j * 3 + c]))) << 32) | (uint32_t)j;
  }
  uint32_t rnk[16];
#pragma unroll
  for (int r = 0; r < 16; ++r) rnk[r] = 0;
  for (int ch = 0; ch < NPRE / 64; ++ch) {
    int j = ch * 64 + ln;
    uint64_t ck = (((uint64_t)(~__float_as_uint(sc3[j * 3 + c]))) << 32) | (uint32_t)j;
#pragma unroll
    for (int r = 0; r < 16; ++r)
      rnk[r] += (uint32_t)__popcll(__ballot(ck < kr[r]));
  }
  uint32_t my_rnk = 0; int my_v = 0;
#pragma unroll
  for (int r = 0; r < 16; ++r) {
    uint32_t sb = ~(uint32_t)(kr[r] >> 32);
    int v = __uint_as_float(sb) > SCORE_THR_F;
    if (ln == r) { my_rnk = rnk[r]; my_v = v; }
  }
  if (ln < 16) {
    ord[c * NPRE + my_rnk] = (uint32_t)(base + ln);
    if (my_v) atomicOr(&vw[c * 64 + (my_rnk >> 6)], 1ull << (my_rnk & 63));
  }
}

// 5) suppression bitmask (upper triangle) + compact diagonal column.
__global__ void k_mask(const uint32_t* __restrict__ ord, const float* __restrict__ box4,
                       const float* __restrict__ areaA, uint64_t* __restrict__ pmask,
                       uint64_t* __restrict__ diagv) {
  int c = blockIdx.z, it = blockIdx.y, jt = blockIdx.x, t = threadIdx.x;
  if (jt < it) return;
  __shared__ float jx1[64], jy1[64], jx2[64], jy2[64], jar[64];
  int j = ord[c * NPRE + jt * 64 + t];
  jx1[t] = box4[j * 4 + 0]; jy1[t] = box4[j * 4 + 1];
  jx2[t] = box4[j * 4 + 2]; jy2[t] = box4[j * 4 + 3];
  jar[t] = areaA[j];
  __syncthreads();
  int I = it * 64 + t;
  int i = ord[c * NPRE + I];
  float x1 = box4[i * 4 + 0], y1 = box4[i * 4 + 1];
  float x2 = box4[i * 4 + 2], y2 = box4[i * 4 + 3];
  float ar = areaA[i];
  uint64_t bits = 0;
  for (int b = 0; b < 64; ++b) {
    float xx1 = fmaxf(x1, jx1[b]), yy1 = fmaxf(y1, jy1[b]);
    float xx2 = fminf(x2, jx2[b]), yy2 = fminf(y2, jy2[b]);
    float iw = fmaxf(0.0f, xx2 - xx1 + 1.0f);
    float ih = fmaxf(0.0f, yy2 - yy1 + 1.0f);
    float inter = iw * ih;
    float iou = inter / (ar + jar[b] - inter);
    bits |= ((uint64_t)(iou > 0.5f)) << b;
  }
  pmask[((size_t)(c * NPRE + I)) * 64 + (size_t)jt] = bits;
  if (jt == it) diagv[(size_t)c * NPRE + (size_t)I] = bits;
}

// 6) single-wave sparse greedy NMS. Counted-vmcnt LDS ring, ISSUE-BEFORE-
//    COMPUTE (issue->wait distance ~= 2 tile-computes > HBM latency), and
//    DEAD-TILE SKIP: avail is monotone-decreasing, so a tile whose avail
//    word is 0 at issue time can never be read -> skip its 32 loads AND its
//    wait. vmcnt drains oldest-first, so vmcnt(32) always leaves exactly the
//    newest batch (T+1 if issued) -> the two-case wait is exact under skips.
__global__ __launch_bounds__(64) void k_nms(const uint64_t* __restrict__ pmask,
                                            const uint64_t* __restrict__ diagv,
                                            const unsigned long long* __restrict__ vw,
                                            uint64_t* __restrict__ keepw) {
  __shared__ uint64_t lb[3 * 4096];   // 96 KB ring
  __shared__ uint64_t dl[4096];       // 32 KB diag columns
  __shared__ uint64_t avl[64];        // 512 B valid words
  const int c = blockIdx.x;
  const int ln = threadIdx.x;  // 0..63
  const uint64_t* pm = pmask + (size_t)c * NPRE * 64;

  const uint32_t* vw32 = (const uint32_t*)(vw + (size_t)c * 64);
  gl_lds4(vw32 + ln, avl);
  gl_lds4(vw32 + 64 + ln, (uint8_t*)avl + 256);
  const uint64_t* gd = diagv + (size_t)c * NPRE;
#pragma unroll
  for (int i = 0; i < 32; ++i) gl_lds16(gd + i * 128 + ln * 2, dl + i * 128);
#pragma unroll
  for (int i = 0; i < 32; ++i) gl_lds16(pm + i * 128 + ln * 2, lb + i * 128);
#pragma unroll
  for (int i = 0; i < 32; ++i) gl_lds16(pm + 4096 + i * 128 + ln * 2, lb + 4096 + i * 128);
  // drain avail+diag (oldest 34); tiles 0,1 stay in flight (HW caps vmcnt at 63)
  asm volatile("s_waitcnt vmcnt(63)" ::: "memory");
  asm volatile("s_waitcnt vmcnt(32)" ::: "memory");  // ensures avail+diag+tile0 done
  __builtin_amdgcn_sched_barrier(0);

  uint64_t avail = avl[ln];
  uint64_t mykeep = 0;
  int cnt = 0;
  bool iss1 = true;  // is tile T+1 issued?
  for (int T = 0; T < 64; ++T) {
    uint64_t dgT = dl[T * 64 + ln];          // LDS, latency hides under wait
    uint64_t awT = readlane64(avail, T);     // wave-uniform word T
    if (awT) {
      if (iss1) { asm volatile("s_waitcnt vmcnt(32)" ::: "memory"); }
      else      { asm volatile("s_waitcnt vmcnt(0)"  ::: "memory"); }
      __builtin_amdgcn_sched_barrier(0);
    }
    // issue tile T+2 (pre-suppression avail: monotone-safe superset)
    bool iss2 = false;
    if (T + 2 < 64) {
      uint64_t aw2 = readlane64(avail, T + 2);
      if (aw2) {
        uint64_t* dst = lb + (size_t)((T + 2) % 3) * 4096;
        const uint64_t* gb = pm + ((size_t)(T + 2) << 12);
#pragma unroll
        for (int i = 0; i < 32; ++i) gl_lds16(gb + i * 128 + ln * 2, dst + i * 128);
        iss2 = true;
      }
    }
    if (awT) {
      const uint64_t* tb = lb + (size_t)(T % 3) * 4096;
      uint64_t kwT = 0;
      while (awT) {                        // each visited row IS a keep
        int r = (int)__builtin_ctzll(awT);
        kwT |= (1ull << r);
        awT &= ~(1ull << r);
        awT &= ~readlane64(dgT, r);
      }
      uint64_t supp = 0, k = kwT;
      while (k) {
        int r0 = (int)__builtin_ctzll(k); k &= k - 1;
        int r1 = k ? (int)__builtin_ctzll(k) : r0; if (k) k &= k - 1;
        int r2 = k ? (int)__builtin_ctzll(k) : r1; if (k) k &= k - 1;
        int r3 = k ? (int)__builtin_ctzll(k) : r2; if (k) k &= k - 1;
        supp |= tb[r0 * 64 + ln] | tb[r1 * 64 + ln] |
                tb[r2 * 64 + ln] | tb[r3 * 64 + ln];
      }
      avail &= ~supp;  // lower-triangle garbage only hits lanes<T (fixed)
      if (ln == T) mykeep = kwT;
      cnt += (int)__popcll(kwT);
      if (cnt >= MAXNUM) break;
      // nothing valid remains in any FUTURE word -> done
      if (__ballot(ln > T && avail != 0) == 0ull) break;
    }
    iss1 = iss2;
  }
  asm volatile("s_waitcnt vmcnt(0)" ::: "memory");
  keepw[c * 64 + ln] = mykeep;
}

// 7) per-class stable-compact first <=500 kept keys into outk[2048] (padded).
__global__ __launch_bounds__(1024) void k_collect(const uint64_t* __restrict__ keepw,
                                                  const uint32_t* __restrict__ ord,
                                                  const float* __restrict__ sc3,
                                                  uint64_t* __restrict__ outk,
                                                  uint32_t* __restrict__ misc) {
  const int c = blockIdx.x, t = threadIdx.x, w = t >> 6, ln = t & 63;
  if (c == 3) {  // tail pad
    int i = 3 * MAXNUM + t;
    if (i < 2048) outk[i] = PADKEY;
    return;
  }
  __shared__ uint32_t wsum[16];
  uint32_t bits4 = 0;
#pragma unroll
  for (int q = 0; q < 4; ++q) {
    int i = t * 4 + q;
    uint32_t b = (uint32_t)((keepw[c * 64 + (i >> 6)] >> (i & 63)) & 1ull);
    bits4 |= b << q;
  }
  uint32_t cnt = __popc(bits4);
  uint32_t incl = cnt;
#pragma unroll
  for (int d = 1; d < 64; d <<= 1) { uint32_t u = __shfl_up(incl, d, 64); if (ln >= d) incl += u; }
  if (ln == 63) wsum[w] = incl;
  __syncthreads();
  uint32_t wb = 0, total = 0;
#pragma unroll
  for (int i = 0; i < 16; ++i) { uint32_t v = wsum[i]; total += v; if (i < w) wb += v; }
  uint32_t r = wb + incl - cnt;  // exclusive prefix
#pragma unroll
  for (int q = 0; q < 4; ++q) {
    if ((bits4 >> q) & 1u) {
      if (r < (uint32_t)MAXNUM) {
        uint32_t pos = ord[c * NPRE + t * 4 + q];
        uint32_t sb = __float_as_uint(sc3[pos * 3 + c]);
        outk[c * MAXNUM + r] = (((uint64_t)(~sb)) << 32) | (uint32_t)(c * NPRE + pos);
      }
      ++r;
    }
  }
  uint32_t Vc = total < (uint32_t)MAXNUM ? total : (uint32_t)MAXNUM;
  if (t == 0) misc[8 + c] = Vc;
  for (uint32_t s = Vc + t; s < (uint32_t)MAXNUM; s += 1024)
    outk[c * MAXNUM + s] = PADKEY;
}

// 8) rank the full 2048-key union; emit rank<500; zero-fill [V,500).
__global__ __launch_bounds__(256) void k_emit(const uint64_t* __restrict__ outk,
                                              const uint32_t* __restrict__ misc,
                                              const float* __restrict__ bb7,
                                              const uint32_t* __restrict__ dsc,
                                              float* __restrict__ out) {
  const int tid = threadIdx.x, ln = tid & 63;
  const int wave = blockIdx.x * 4 + (tid >> 6);  // 0..127
  const int base = wave * 16;                    // rows 0..2047
  uint64_t kr[16];
#pragma unroll
  for (int r = 0; r < 16; ++r) kr[r] = outk[base + r];
  uint32_t rnk[16];
#pragma unroll
  for (int r = 0; r < 16; ++r) rnk[r] = 0;
  for (int ch = 0; ch < 2048 / 64; ++ch) {
    uint64_t ck = outk[ch * 64 + ln];
#pragma unroll
    for (int r = 0; r < 16; ++r)
      rnk[r] += (uint32_t)__popcll(__ballot(ck < kr[r]));
  }
  if (ln == 0) {
#pragma unroll
    for (int r = 0; r < 16; ++r) {
      uint64_t key = kr[r];
      uint32_t rk = rnk[r];
      if (key != PADKEY && rk < (uint32_t)MAXNUM) {
        uint32_t flat = (uint32_t)key;
        float score = __uint_as_float(~((uint32_t)(key >> 32)));
        int cc = (int)(flat >> 12);
        int pos = (int)(flat & 4095u);
        const float* b = bb7 + (size_t)pos * 7;
        float rr0 = b[6];
        float dir_rot = rr0 + HPIF - floorf(rr0 + 0.5f) * PIF;
        float rr = dir_rot - HPIF + PIF * (float)dsc[pos];
#pragma unroll
        for (int q = 0; q < 6; ++q) out[rk * 7 + q] = b[q];
        out[rk * 7 + 6] = rr;
        out[7 * MAXNUM + rk] = score;
        out[8 * MAXNUM + rk] = (float)cc;
      }
    }
  }
  if (blockIdx.x == 0) {
    uint32_t V = misc[8] + misc[9] + misc[10];
    for (uint32_t s = V + tid; s < (uint32_t)MAXNUM; s += 256) {
#pragma unroll
      for (int q = 0; q < 7; ++q) out[s * 7 + q] = 0.0f;
      out[7 * MAXNUM + s] = 0.0f;
      out[8 * MAXNUM + s] = -1.0f;
    }
  }
}

// ---------------- launcher ----------------
extern "C" void kernel_launch(void* const* d_in, const int* in_sizes, int n_in,
                              void* d_out, int out_size, void* d_ws, size_t ws_size,
                              hipStream_t stream) {
  (void)in_sizes; (void)n_in; (void)out_size; (void)ws_size;
  const float* cls    = (const float*)d_in[0];
  const float* bbp    = (const float*)d_in[1];
  const float* dirp   = (const float*)d_in[2];
  const float* priors = (const float*)d_in[3];
  char* ws = (char*)d_ws;

  uint32_t* hist   = (uint32_t*)(ws + HIST_OFF);
  uint32_t* misc   = (uint32_t*)(ws + MISC_OFF);
  unsigned long long* vw = (unsigned long long*)(ws + VW_OFF);
  float*    ms     = (float*)(ws + MS_OFF);
  uint64_t* cand   = (uint64_t*)(ws + CAND_OFF);
  float*    sc3    = (float*)(ws + SC3_OFF);
  uint32_t* dsc    = (uint32_t*)(ws + DSC_OFF);
  float*    bb7    = (float*)(ws + BB7_OFF);
  float*    box4   = (float*)(ws + BOX4_OFF);
  float*    areaA  = (float*)(ws + AREA_OFF);
  uint32_t* ord    = (uint32_t*)(ws + ORD_OFF);
  uint64_t* pmask  = (uint64_t*)(ws + PMASK_OFF);
  uint64_t* keepw  = (uint64_t*)(ws + KEEPW_OFF);
  uint64_t* outk   = (uint64_t*)(ws + OUTK_OFF);
  uint64_t* diagv  = (uint64_t*)(ws + DIAG_OFF);

  hipMemsetAsync(ws, 0, ZERO_BYTES, stream);  // hist + misc + vw in one call
  k_score<<<NB_H, 256, 0, stream>>>(cls, ms, hist);
  k_compact<<<(NANCH + 4095) / 4096, 256, 0, stream>>>(ms, hist, misc, cand);
  k_rankgather<<<128, 256, 0, stream>>>(cand, misc, cls, bbp, dirp, priors,
                                        sc3, dsc, bb7, box4, areaA);
  k_rankcls<<<dim3(NPRE / (4 * 16), 3), 256, 0, stream>>>(sc3, ord, vw);
  k_mask<<<dim3(64, 64, 3), 64, 0, stream>>>(ord, box4, areaA, pmask, diagv);
  k_nms<<<3, 64, 0, stream>>>(pmask, diagv, vw, keepw);
  k_collect<<<4, 1024, 0, stream>>>(keepw, ord, sc3, outk, misc);
  k_emit<<<2048 / (4 * 16), 256, 0, stream>>>(outk, misc, bb7, dsc, (float*)d_out);
}

// Round 5
// 259.085 us; speedup vs baseline: 1.6579x; 1.1666x over previous
//
#include <hip/hip_runtime.h>
#include <stdint.h>
#include <stddef.h>

// ---------------- problem constants ----------------
constexpr int kH = 496, kW = 432;
constexpr int HWSZ = kH * kW;          // 214272
constexpr int NANCH = HWSZ * 6;        // 1285632 anchors
constexpr int NPRE = 4096;             // nms_pre
constexpr int MAXNUM = 500;
constexpr int CAND_CAP = 8192;
constexpr float SCORE_THR_F = 0.1f;
constexpr float PIF  = 3.14159265358979323846f;
constexpr float HPIF = 1.57079632679489661923f;

constexpr int NBINS  = 32768;
constexpr int NPAIR  = NBINS / 2;      // packed u16 pairs in LDS = 64 KB
constexpr int NB_H   = 256;            // histogram blocks
constexpr uint64_t PADKEY = 0xFFFFFFFF00000000ull;

// ---------------- workspace layout (bytes) ----------------
constexpr size_t HIST_OFF  = 0;                                   // u32[32768] = 128 KB
constexpr size_t MISC_OFF  = 131072;                              // u32[64]
constexpr size_t VW_OFF    = 131328;                              // u64[3*64] = 1536 B
constexpr size_t ZERO_BYTES= 131328 + 1536;                       // hist+misc+vw, ONE memset
constexpr size_t MS_OFF    = ZERO_BYTES;                          // f32[NANCH]
constexpr size_t CAND_OFF  = MS_OFF + 4ull * NANCH;               // u64[8192]
constexpr size_t SC3_OFF   = CAND_OFF + 8ull * CAND_CAP;          // f32[NPRE*3]
constexpr size_t DSC_OFF   = SC3_OFF + 4ull * NPRE * 3;           // u32[NPRE]
constexpr size_t BB7_OFF   = DSC_OFF + 4ull * NPRE;               // f32[NPRE*7]
constexpr size_t BOX4_OFF  = BB7_OFF + 4ull * NPRE * 7;           // f32[NPRE*4]
constexpr size_t AREA_OFF  = BOX4_OFF + 4ull * NPRE * 4;          // f32[NPRE]
constexpr size_t ORD_OFF   = AREA_OFF + 4ull * NPRE;              // u32[3*NPRE]
constexpr size_t PMASK_OFF = ORD_OFF + 4ull * 3 * NPRE;           // u64[3*NPRE*64] (6 MB)
constexpr size_t KEEPW_OFF = PMASK_OFF + 8ull * 3 * NPRE * 64;    // u64[3*64]
constexpr size_t OUTK_OFF  = KEEPW_OFF + 8ull * 3 * 64;           // u64[2048]
constexpr size_t DIAG_OFF  = OUTK_OFF + 8ull * 2048;              // u64[3*NPRE]

// ---------------- helpers ----------------
__device__ __forceinline__ float sigmoidf_(float x) { return 1.0f / (1.0f + expf(-x)); }

__device__ __forceinline__ uint64_t readlane64(uint64_t v, int lane) {
  uint32_t lo = (uint32_t)__builtin_amdgcn_readlane((int)(uint32_t)(v & 0xffffffffull), lane);
  uint32_t hi = (uint32_t)__builtin_amdgcn_readlane((int)(uint32_t)(v >> 32), lane);
  return (((uint64_t)hi) << 32) | (uint64_t)lo;
}

__device__ __forceinline__ void gl_lds16(const uint64_t* g, void* l) {
  __builtin_amdgcn_global_load_lds(
      (const __attribute__((address_space(1))) void*)g,
      (__attribute__((address_space(3))) void*)l, 16, 0, 0);
}
__device__ __forceinline__ void gl_lds4(const uint32_t* g, void* l) {
  __builtin_amdgcn_global_load_lds(
      (const __attribute__((address_space(1))) void*)g,
      (__attribute__((address_space(3))) void*)l, 4, 0, 0);
}

// ---------------- kernels ----------------

// 1) per-anchor max-of-3-sigmoids + per-block LDS histogram.
__global__ __launch_bounds__(256) void k_score(const float* __restrict__ cls,
                                               float* __restrict__ ms,
                                               uint32_t* __restrict__ hist) {
  __shared__ uint32_t h[NPAIR];  // 64 KB, packed u16 pairs
  const int t = threadIdx.x, blk = blockIdx.x;
  for (int i = t; i < NPAIR; i += 256) h[i] = 0;
  __syncthreads();
  for (int p = blk * 256 + t; p < HWSZ; p += NB_H * 256) {
#pragma unroll
    for (int k = 0; k < 6; ++k) {
      float s0 = sigmoidf_(cls[(k * 3 + 0) * HWSZ + p]);
      float s1 = sigmoidf_(cls[(k * 3 + 1) * HWSZ + p]);
      float s2 = sigmoidf_(cls[(k * 3 + 2) * HWSZ + p]);
      float m = fmaxf(s0, fmaxf(s1, s2));
      ms[p * 6 + k] = m;
      uint32_t bin = __float_as_uint(m) >> 15;  // < 32768 (scores < 2.0)
      atomicAdd(&h[bin >> 1], 1u << ((bin & 1) * 16));
    }
  }
  __syncthreads();
  for (int i = t; i < NPAIR; i += 256) {
    uint32_t v = h[i];
    if (v) {
      uint32_t lo = v & 0xFFFFu, hi = v >> 16;
      if (lo) atomicAdd(&hist[2 * i],     lo);
      if (hi) atomicAdd(&hist[2 * i + 1], hi);
    }
  }
}

// 2) block-aggregated compaction with FUSED threshold scan (hist L2-resident).
__global__ __launch_bounds__(256) void k_compact(const float* __restrict__ ms,
                                                 const uint32_t* __restrict__ hist,
                                                 uint32_t* __restrict__ misc,
                                                 uint64_t* __restrict__ cand) {
  constexpr int APB = 4096;
  __shared__ uint64_t lbuf[APB];       // 32 KB
  __shared__ uint32_t suf[256];
  __shared__ uint32_t win[256];
  __shared__ uint32_t lcnt, lbase, sWin, sAbove, sB;
  const int t = threadIdx.x;
  const int base = blockIdx.x * APB;

  uint32_t s = 0;
  const int hbase = t * 128;
#pragma unroll 16
  for (int i = 0; i < 128; ++i) s += hist[hbase + i];
  suf[t] = s;
  if (t == 0) { lcnt = 0; sB = 0; }
  __syncthreads();
  for (int d = 1; d < 256; d <<= 1) {
    uint32_t v = suf[t] + ((t + d < 256) ? suf[t + d] : 0u);
    __syncthreads(); suf[t] = v; __syncthreads();
  }
  {
    uint32_t sin = suf[t];
    uint32_t sup = (t < 255) ? suf[t + 1] : 0u;
    if (sin >= (uint32_t)NPRE && sup < (uint32_t)NPRE) { sWin = (uint32_t)t; sAbove = sup; }
  }
  __syncthreads();
  const uint32_t wbase = sWin * 128u;
  win[t] = (t < 128) ? hist[wbase + (uint32_t)t] : 0u;
  __syncthreads();
  for (int d = 1; d < 256; d <<= 1) {
    uint32_t v = win[t] + ((t + d < 256) ? win[t + d] : 0u);
    __syncthreads(); win[t] = v; __syncthreads();
  }
  if (t < 128 && sAbove + win[t] >= (uint32_t)NPRE)
    atomicMax(&sB, wbase + (uint32_t)t);
  __syncthreads();
  const uint32_t B = sB;

#pragma unroll
  for (int q = 0; q < 16; ++q) {
    int a = base + q * 256 + t;
    if (a < NANCH) {
      uint32_t bits = __float_as_uint(ms[a]);
      if ((bits >> 15) >= B) {
        uint32_t sl = atomicAdd(&lcnt, 1u);
        lbuf[sl] = (((uint64_t)(~bits)) << 32) | (uint32_t)a;
      }
    }
  }
  __syncthreads();
  const uint32_t n = lcnt;
  if (t == 0 && n > 0) lbase = atomicAdd(&misc[0], n);
  __syncthreads();
  if (n > 0) {
    const uint32_t b0 = lbase;
    for (uint32_t i = t; i < n; i += 256) {
      uint32_t slot = b0 + i;
      if (slot < (uint32_t)CAND_CAP) cand[slot] = lbuf[i];
    }
  }
}

// 3) FUSED rank + gather/decode: 8 rows/wave (shorter serial ballot chain,
//    2x the waves vs 16-row version). Ranks wave-uniform -> lane r decodes row r.
__global__ __launch_bounds__(256) void k_rankgather(const uint64_t* __restrict__ cand,
                                                    const uint32_t* __restrict__ misc,
                                                    const float* __restrict__ cls,
                                                    const float* __restrict__ bbp,
                                                    const float* __restrict__ dirp,
                                                    const float* __restrict__ priors,
                                                    float* __restrict__ sc3,
                                                    uint32_t* __restrict__ dsc,
                                                    float* __restrict__ bb7,
                                                    float* __restrict__ box4,
                                                    float* __restrict__ areaA) {
  const int tid = threadIdx.x, ln = tid & 63;
  const int wave = blockIdx.x * 4 + (tid >> 6);   // 0..1023
  const int base = wave * 8;
  uint32_t cnt = misc[0];
  if (cnt > (uint32_t)CAND_CAP) cnt = CAND_CAP;
  uint64_t kr[8];
#pragma unroll
  for (int r = 0; r < 8; ++r) kr[r] = cand[base + r];
  uint32_t rnk[8];
#pragma unroll
  for (int r = 0; r < 8; ++r) rnk[r] = 0;
  const int nch = ((int)cnt + 63) >> 6;
  for (int ch = 0; ch < nch; ++ch) {
    uint64_t ck = cand[ch * 64 + ln];
    uint64_t vm = __ballot(ch * 64 + ln < (int)cnt);
#pragma unroll
    for (int r = 0; r < 8; ++r)
      rnk[r] += (uint32_t)__popcll(__ballot(ck < kr[r]) & vm);
  }
  uint32_t my_a = 0, my_i = 0; int my_ok = 0;
#pragma unroll
  for (int r = 0; r < 8; ++r) {
    int ok = (base + r < (int)cnt) && (rnk[r] < (uint32_t)NPRE);
    if (ln == r) { my_a = (uint32_t)kr[r]; my_i = rnk[r]; my_ok = ok; }
  }
  if (ln < 8 && my_ok) {
    uint32_t a = my_a, i = my_i;
    uint32_t p = a / 6u;
    uint32_t k = a - p * 6u;
#pragma unroll
    for (int c = 0; c < 3; ++c) sc3[i * 3 + c] = sigmoidf_(cls[(k * 3 + c) * HWSZ + p]);
    float d0 = dirp[(k * 2 + 0) * HWSZ + p];
    float d1 = dirp[(k * 2 + 1) * HWSZ + p];
    dsc[i] = (d1 > d0) ? 1u : 0u;
    float dt[7], pr[7];
#pragma unroll
    for (int q = 0; q < 7; ++q) dt[q] = bbp[(k * 7 + q) * HWSZ + p];
#pragma unroll
    for (int q = 0; q < 7; ++q) pr[q] = priors[(size_t)a * 7 + q];
    float za = pr[2] + pr[5] * 0.5f;
    float diag = sqrtf(pr[4] * pr[4] + pr[3] * pr[3]);
    float xg = dt[0] * diag + pr[0];
    float yg = dt[1] * diag + pr[1];
    float zg = dt[2] * pr[5] + za;
    float wg = expf(dt[3]) * pr[3];
    float lg = expf(dt[4]) * pr[4];
    float hg = expf(dt[5]) * pr[5];
    float rg = dt[6] + pr[6];
    zg = zg - hg * 0.5f;
    bb7[i * 7 + 0] = xg; bb7[i * 7 + 1] = yg; bb7[i * 7 + 2] = zg;
    bb7[i * 7 + 3] = wg; bb7[i * 7 + 4] = lg; bb7[i * 7 + 5] = hg; bb7[i * 7 + 6] = rg;
    float x1 = xg - wg * 0.5f, y1 = yg - lg * 0.5f;
    float x2 = xg + wg * 0.5f, y2 = yg + lg * 0.5f;
    box4[i * 4 + 0] = x1; box4[i * 4 + 1] = y1; box4[i * 4 + 2] = x2; box4[i * 4 + 3] = y2;
    areaA[i] = (x2 - x1 + 1.0f) * (y2 - y1 + 1.0f);
  }
}

// 4) per-class rank -> ord (8 rows/wave), + vwords bitset via atomicOr scatter.
__global__ __launch_bounds__(256) void k_rankcls(const float* __restrict__ sc3,
                                                 uint32_t* __restrict__ ord,
                                                 unsigned long long* __restrict__ vw) {
  const int tid = threadIdx.x, ln = tid & 63;
  const int c = blockIdx.y;
  const int wave = blockIdx.x * 4 + (tid >> 6);  // 0..511
  const int base = wave * 8;
  uint64_t kr[8];
#pragma unroll
  for (int r = 0; r < 8; ++r) {
    int j = base + r;
    kr[r] = (((uint64_t)(~__float_as_uint(sc3[j * 3 + c]))) << 32) | (uint32_t)j;
  }
  uint32_t rnk[8];
#pragma unroll
  for (int r = 0; r < 8; ++r) rnk[r] = 0;
  for (int ch = 0; ch < NPRE / 64; ++ch) {
    int j = ch * 64 + ln;
    uint64_t ck = (((uint64_t)(~__float_as_uint(sc3[j * 3 + c]))) << 32) | (uint32_t)j;
#pragma unroll
    for (int r = 0; r < 8; ++r)
      rnk[r] += (uint32_t)__popcll(__ballot(ck < kr[r]));
  }
  uint32_t my_rnk = 0; int my_v = 0;
#pragma unroll
  for (int r = 0; r < 8; ++r) {
    uint32_t sb = ~(uint32_t)(kr[r] >> 32);
    int v = __uint_as_float(sb) > SCORE_THR_F;
    if (ln == r) { my_rnk = rnk[r]; my_v = v; }
  }
  if (ln < 8) {
    ord[c * NPRE + my_rnk] = (uint32_t)(base + ln);
    if (my_v) atomicOr(&vw[c * 64 + (my_rnk >> 6)], 1ull << (my_rnk & 63));
  }
}

// 5) suppression bitmask (upper triangle, compact 1-D triangular grid) + diag.
__global__ __launch_bounds__(64) void k_mask(const uint32_t* __restrict__ ord,
                                             const float* __restrict__ box4,
                                             const float* __restrict__ areaA,
                                             uint64_t* __restrict__ pmask,
                                             uint64_t* __restrict__ diagv) {
  const int t = threadIdx.x;
  int task = blockIdx.x;              // 0..6239 (3 x 2080 upper-tri tiles)
  const int c = task / 2080;
  int rr = task - c * 2080;
  int it = 0;
  while (rr >= 64 - it) { rr -= 64 - it; ++it; }
  const int jt = it + rr;

  __shared__ float jx1[64], jy1[64], jx2[64], jy2[64], jar[64];
  int j = ord[c * NPRE + jt * 64 + t];
  jx1[t] = box4[j * 4 + 0]; jy1[t] = box4[j * 4 + 1];
  jx2[t] = box4[j * 4 + 2]; jy2[t] = box4[j * 4 + 3];
  jar[t] = areaA[j];
  __syncthreads();
  int I = it * 64 + t;
  int i = ord[c * NPRE + I];
  float x1 = box4[i * 4 + 0], y1 = box4[i * 4 + 1];
  float x2 = box4[i * 4 + 2], y2 = box4[i * 4 + 3];
  float ar = areaA[i];
  uint64_t bits = 0;
  for (int b = 0; b < 64; ++b) {
    float xx1 = fmaxf(x1, jx1[b]), yy1 = fmaxf(y1, jy1[b]);
    float xx2 = fminf(x2, jx2[b]), yy2 = fminf(y2, jy2[b]);
    float iw = fmaxf(0.0f, xx2 - xx1 + 1.0f);
    float ih = fmaxf(0.0f, yy2 - yy1 + 1.0f);
    float inter = iw * ih;
    float iou = inter / (ar + jar[b] - inter);
    bits |= ((uint64_t)(iou > 0.5f)) << b;
  }
  pmask[((size_t)(c * NPRE + I)) * 64 + (size_t)jt] = bits;
  if (jt == it) diagv[(size_t)c * NPRE + (size_t)I] = bits;
}

// 6) single-wave sparse greedy NMS v3.
//    - counted-vmcnt LDS ring, unconditional depth-2 prefetch
//    - IN-TILE FAST PATH: IoU matrix is symmetric, so if no live pair in the
//      tile suppresses each other (one and+ballot on the register diag
//      column), greedy keeps ALL live rows -> skip the ~63-step serial
//      recurrence. Exact: falls back to the serial loop otherwise.
//    - BRANCH-FREE SUPP OR: 64 unconditional statically-addressed
//      ds_read_b64 + SGPR-predicated mask, replacing the dependent-ctz chain
//      (independent loads pipeline; ~700cy vs ~2000cy).
//    - break at 500 BEFORE the supp OR (last tile's OR is dead work).
__global__ __launch_bounds__(64) void k_nms(const uint64_t* __restrict__ pmask,
                                            const uint64_t* __restrict__ diagv,
                                            const unsigned long long* __restrict__ vw,
                                            uint64_t* __restrict__ keepw) {
  __shared__ uint64_t lb[3 * 4096];   // 96 KB ring
  __shared__ uint64_t dl[4096];       // 32 KB diag columns
  __shared__ uint64_t avl[64];        // 512 B valid words
  const int c = blockIdx.x;
  const int ln = threadIdx.x;  // 0..63
  const uint64_t* pm = pmask + (size_t)c * NPRE * 64;

  const uint32_t* vw32 = (const uint32_t*)(vw + (size_t)c * 64);
  gl_lds4(vw32 + ln, avl);
  gl_lds4(vw32 + 64 + ln, (uint8_t*)avl + 256);
  const uint64_t* gd = diagv + (size_t)c * NPRE;
#pragma unroll
  for (int i = 0; i < 32; ++i) gl_lds16(gd + i * 128 + ln * 2, dl + i * 128);
#pragma unroll
  for (int i = 0; i < 32; ++i) gl_lds16(pm + i * 128 + ln * 2, lb + i * 128);
#pragma unroll
  for (int i = 0; i < 32; ++i) gl_lds16(pm + 4096 + i * 128 + ln * 2, lb + 4096 + i * 128);
  // >=63 outstanding throttles at HW cap; this waits until only tile1 (newest
  // 32) is in flight -> avail+diag+tile0 arrived.
  asm volatile("s_waitcnt vmcnt(32)" ::: "memory");
  __builtin_amdgcn_sched_barrier(0);

  uint64_t avail = avl[ln];
  uint64_t mykeep = 0;
  int cnt = 0;
  for (int T = 0; T < 64; ++T) {
    uint64_t dgT = dl[T * 64 + ln];          // LDS (lgkmcnt), independent of vmcnt
    if (T > 0) {
      if (T < 63) { asm volatile("s_waitcnt vmcnt(32)" ::: "memory"); }
      else        { asm volatile("s_waitcnt vmcnt(0)"  ::: "memory"); }
      __builtin_amdgcn_sched_barrier(0);
    }
    // issue tile T+2 immediately after the wait (max issue->wait distance)
    if (T + 2 < 64) {
      uint64_t* dst = lb + (size_t)((T + 2) % 3) * 4096;
      const uint64_t* gb = pm + ((size_t)(T + 2) << 12);
#pragma unroll
      for (int i = 0; i < 32; ++i) gl_lds16(gb + i * 128 + ln * 2, dst + i * 128);
    }

    uint64_t awT = readlane64(avail, T);     // wave-uniform word T
    if (awT) {
      // ---- in-tile keep set ----
      uint64_t kwT;
      uint64_t conf = dgT & awT & ~(1ull << ln);          // live boxes hitting me
      bool bad = ((awT >> ln) & 1ull) && (conf != 0ull);  // live pair conflict?
      if (__ballot(bad) == 0ull) {
        kwT = awT;                            // fast path: keep all live
      } else {
        uint64_t aw = awT;                    // exact serial fallback
        kwT = 0;
        while (aw) {
          int r = (int)__builtin_ctzll(aw);
          kwT |= (1ull << r);
          aw &= ~(1ull << r);
          aw &= ~readlane64(dgT, r);
        }
      }
      if (ln == T) mykeep = kwT;
      cnt += (int)__popcll(kwT);
      if (cnt >= MAXNUM) break;               // 500 reached: supp OR is dead work

      // ---- apply suppression to future words: predicated 64-way LDS OR ----
      const uint64_t* tb = lb + (size_t)(T % 3) * 4096;
      uint64_t supp = 0;
#pragma unroll
      for (int r = 0; r < 64; ++r) {
        uint64_t msk = (uint64_t)0 - ((kwT >> r) & 1ull);  // all-ones if kept
        supp |= tb[r * 64 + ln] & msk;
      }
      avail &= ~supp;  // lower-triangle garbage only hits lanes<T (fixed)
      if (__ballot(ln > T && avail != 0) == 0ull) break;   // nothing left ahead
    }
  }
  asm volatile("s_waitcnt vmcnt(0)" ::: "memory");
  keepw[c * 64 + ln] = mykeep;
}

// 7) per-class stable-compact first <=500 kept keys into outk[2048] (padded).
__global__ __launch_bounds__(1024) void k_collect(const uint64_t* __restrict__ keepw,
                                                  const uint32_t* __restrict__ ord,
                                                  const float* __restrict__ sc3,
                                                  uint64_t* __restrict__ outk,
                                                  uint32_t* __restrict__ misc) {
  const int c = blockIdx.x, t = threadIdx.x, w = t >> 6, ln = t & 63;
  if (c == 3) {  // tail pad
    int i = 3 * MAXNUM + t;
    if (i < 2048) outk[i] = PADKEY;
    return;
  }
  __shared__ uint32_t wsum[16];
  uint32_t bits4 = 0;
#pragma unroll
  for (int q = 0; q < 4; ++q) {
    int i = t * 4 + q;
    uint32_t b = (uint32_t)((keepw[c * 64 + (i >> 6)] >> (i & 63)) & 1ull);
    bits4 |= b << q;
  }
  uint32_t cnt = __popc(bits4);
  uint32_t incl = cnt;
#pragma unroll
  for (int d = 1; d < 64; d <<= 1) { uint32_t u = __shfl_up(incl, d, 64); if (ln >= d) incl += u; }
  if (ln == 63) wsum[w] = incl;
  __syncthreads();
  uint32_t wb = 0, total = 0;
#pragma unroll
  for (int i = 0; i < 16; ++i) { uint32_t v = wsum[i]; total += v; if (i < w) wb += v; }
  uint32_t r = wb + incl - cnt;  // exclusive prefix
#pragma unroll
  for (int q = 0; q < 4; ++q) {
    if ((bits4 >> q) & 1u) {
      if (r < (uint32_t)MAXNUM) {
        uint32_t pos = ord[c * NPRE + t * 4 + q];
        uint32_t sb = __float_as_uint(sc3[pos * 3 + c]);
        outk[c * MAXNUM + r] = (((uint64_t)(~sb)) << 32) | (uint32_t)(c * NPRE + pos);
      }
      ++r;
    }
  }
  uint32_t Vc = total < (uint32_t)MAXNUM ? total : (uint32_t)MAXNUM;
  if (t == 0) misc[8 + c] = Vc;
  for (uint32_t s = Vc + t; s < (uint32_t)MAXNUM; s += 1024)
    outk[c * MAXNUM + s] = PADKEY;
}

// 8) rank the full 2048-key union (8 rows/wave); emit rank<500; zero-fill tail.
__global__ __launch_bounds__(256) void k_emit(const uint64_t* __restrict__ outk,
                                              const uint32_t* __restrict__ misc,
                                              const float* __restrict__ bb7,
                                              const uint32_t* __restrict__ dsc,
                                              float* __restrict__ out) {
  const int tid = threadIdx.x, ln = tid & 63;
  const int wave = blockIdx.x * 4 + (tid >> 6);  // 0..255
  const int base = wave * 8;                     // rows 0..2047
  uint64_t kr[8];
#pragma unroll
  for (int r = 0; r < 8; ++r) kr[r] = outk[base + r];
  uint32_t rnk[8];
#pragma unroll
  for (int r = 0; r < 8; ++r) rnk[r] = 0;
  for (int ch = 0; ch < 2048 / 64; ++ch) {
    uint64_t ck = outk[ch * 64 + ln];
#pragma unroll
    for (int r = 0; r < 8; ++r)
      rnk[r] += (uint32_t)__popcll(__ballot(ck < kr[r]));
  }
  if (ln == 0) {
#pragma unroll
    for (int r = 0; r < 8; ++r) {
      uint64_t key = kr[r];
      uint32_t rk = rnk[r];
      if (key != PADKEY && rk < (uint32_t)MAXNUM) {
        uint32_t flat = (uint32_t)key;
        float score = __uint_as_float(~((uint32_t)(key >> 32)));
        int cc = (int)(flat >> 12);
        int pos = (int)(flat & 4095u);
        const float* b = bb7 + (size_t)pos * 7;
        float rr0 = b[6];
        float dir_rot = rr0 + HPIF - floorf(rr0 + 0.5f) * PIF;
        float rr = dir_rot - HPIF + PIF * (float)dsc[pos];
#pragma unroll
        for (int q = 0; q < 6; ++q) out[rk * 7 + q] = b[q];
        out[rk * 7 + 6] = rr;
        out[7 * MAXNUM + rk] = score;
        out[8 * MAXNUM + rk] = (float)cc;
      }
    }
  }
  if (blockIdx.x == 0) {
    uint32_t V = misc[8] + misc[9] + misc[10];
    for (uint32_t s = V + tid; s < (uint32_t)MAXNUM; s += 256) {
#pragma unroll
      for (int q = 0; q < 7; ++q) out[s * 7 + q] = 0.0f;
      out[7 * MAXNUM + s] = 0.0f;
      out[8 * MAXNUM + s] = -1.0f;
    }
  }
}

// ---------------- launcher ----------------
extern "C" void kernel_launch(void* const* d_in, const int* in_sizes, int n_in,
                              void* d_out, int out_size, void* d_ws, size_t ws_size,
                              hipStream_t stream) {
  (void)in_sizes; (void)n_in; (void)out_size; (void)ws_size;
  const float* cls    = (const float*)d_in[0];
  const float* bbp    = (const float*)d_in[1];
  const float* dirp   = (const float*)d_in[2];
  const float* priors = (const float*)d_in[3];
  char* ws = (char*)d_ws;

  uint32_t* hist   = (uint32_t*)(ws + HIST_OFF);
  uint32_t* misc   = (uint32_t*)(ws + MISC_OFF);
  unsigned long long* vw = (unsigned long long*)(ws + VW_OFF);
  float*    ms     = (float*)(ws + MS_OFF);
  uint64_t* cand   = (uint64_t*)(ws + CAND_OFF);
  float*    sc3    = (float*)(ws + SC3_OFF);
  uint32_t* dsc    = (uint32_t*)(ws + DSC_OFF);
  float*    bb7    = (float*)(ws + BB7_OFF);
  float*    box4   = (float*)(ws + BOX4_OFF);
  float*    areaA  = (float*)(ws + AREA_OFF);
  uint32_t* ord    = (uint32_t*)(ws + ORD_OFF);
  uint64_t* pmask  = (uint64_t*)(ws + PMASK_OFF);
  uint64_t* keepw  = (uint64_t*)(ws + KEEPW_OFF);
  uint64_t* outk   = (uint64_t*)(ws + OUTK_OFF);
  uint64_t* diagv  = (uint64_t*)(ws + DIAG_OFF);

  hipMemsetAsync(ws, 0, ZERO_BYTES, stream);  // hist + misc + vw in one call
  k_score<<<NB_H, 256, 0, stream>>>(cls, ms, hist);
  k_compact<<<(NANCH + 4095) / 4096, 256, 0, stream>>>(ms, hist, misc, cand);
  k_rankgather<<<256, 256, 0, stream>>>(cand, misc, cls, bbp, dirp, priors,
                                        sc3, dsc, bb7, box4, areaA);
  k_rankcls<<<dim3(128, 3), 256, 0, stream>>>(sc3, ord, vw);
  k_mask<<<6240, 64, 0, stream>>>(ord, box4, areaA, pmask, diagv);
  k_nms<<<3, 64, 0, stream>>>(pmask, diagv, vw, keepw);
  k_collect<<<4, 1024, 0, stream>>>(keepw, ord, sc3, outk, misc);
  k_emit<<<64, 256, 0, stream>>>(outk, misc, bb7, dsc, (float*)d_out);
}